// Round 11
// baseline (558.828 us; speedup 1.0000x reference)
//
#include <hip/hip_runtime.h>
#include <stdint.h>

typedef unsigned short u16;
typedef _Float16 f16x8 __attribute__((ext_vector_type(8)));
typedef float f32x4 __attribute__((ext_vector_type(4)));

#define B_   4
#define S_   2048
#define D_   1024
#define ND3  3072

__device__ __forceinline__ u16 f2h(float x) {
    union { _Float16 h; u16 u; } v; v.h = (_Float16)x; return v.u;
}

__device__ __forceinline__ void gload_lds16(const u16* g, u16* l) {
    __builtin_amdgcn_global_load_lds((const __attribute__((address_space(1))) void*)g,
                                     (__attribute__((address_space(3))) void*)l, 16, 0, 0);
}

// bijective XCD swizzle for nwg % 8 == 0
__device__ __forceinline__ int xcd_swz(int lid, int nwg) {
    int c = nwg >> 3;
    return (lid & 7) * c + (lid >> 3);
}

// ============ 128x256 fp16 GEMM core, K-step=32 double-buffer ============
// acc += A @ B^T, K = NT*64 (steps of 32). 512 threads = 8 waves (2Mrow x 4Ncol),
// per-wave output 64x64, acc[4][4]. LDS 48KB: A [2][128r][32k] + B [2][256r][32k].
// Swizzle: chunk c of row r stored at c ^ ((r>>1)&3), applied on global SOURCE
// (linear LDS dest) and identically on ds_read. Race-free step (proven r7/r8):
//   lgkmcnt(0); barrier; ISSUE(S+1); vmcnt(3); barrier; body (8 ds_read + 16 MFMA).
template<int NT>
__device__ __forceinline__ void gemm_wide(const u16* __restrict__ A, const u16* __restrict__ Bt,
                                          int lda, int ldb, int rowbase, int colbase,
                                          u16* ldsA, u16* ldsB, f32x4 (&acc)[4][4])
{
    const int NSTEP = 2 * NT;
    const int tid  = threadIdx.x;
    const int lane = tid & 63;
    const int w    = tid >> 6;
    const int wr   = w >> 2, wc = w & 3;

    const int r0 = tid >> 2;
    const int c0 = (((tid & 3) ^ ((tid >> 3) & 3)) << 3);
    const uint32_t offA0 = (uint32_t)(rowbase + r0) * lda + c0;
    const uint32_t offB0 = (uint32_t)(colbase + r0) * ldb + c0;
    const uint32_t offB1 = offB0 + (uint32_t)128 * ldb;
    const int dst = tid << 3;

    const int rd_lane = ((lane & 15) << 5) + ((((lane >> 4) ^ (lane >> 1)) & 3) << 3);
    const int wrOff = wr << 11;
    const int wcOff = wc << 11;

#define ISSUE(sv) do { int s_ = (sv); \
    if (s_ < NSTEP) { \
        uint32_t ko_ = (uint32_t)s_ << 5; \
        int slA_ = (s_ & 1) << 12, slB_ = (s_ & 1) << 13; \
        gload_lds16(A  + offA0 + ko_, ldsA + slA_ + dst); \
        gload_lds16(Bt + offB0 + ko_, ldsB + slB_ + dst); \
        gload_lds16(Bt + offB1 + ko_, ldsB + slB_ + dst + 4096); \
    } } while (0)

    f16x8 af[4], bf[4];

#define STEP(sv, slA, slB) { \
    asm volatile("s_waitcnt lgkmcnt(0)" ::: "memory"); \
    __builtin_amdgcn_s_barrier(); \
    asm volatile("" ::: "memory"); \
    ISSUE((sv) + 1); \
    if ((sv) < NSTEP - 1) asm volatile("s_waitcnt vmcnt(3)" ::: "memory"); \
    else                  asm volatile("s_waitcnt vmcnt(0)" ::: "memory"); \
    __builtin_amdgcn_s_barrier(); \
    asm volatile("" ::: "memory"); \
    _Pragma("unroll") for (int mq = 0; mq < 4; ++mq) \
        af[mq] = *(const f16x8*)(ldsA + (slA) + wrOff + (mq << 9) + rd_lane); \
    _Pragma("unroll") for (int n = 0; n < 4; ++n) \
        bf[n] = *(const f16x8*)(ldsB + (slB) + wcOff + (n << 9) + rd_lane); \
    _Pragma("unroll") for (int mq = 0; mq < 4; ++mq) \
    _Pragma("unroll") for (int n = 0; n < 4; ++n) \
        acc[mq][n] = __builtin_amdgcn_mfma_f32_16x16x32_f16(af[mq], bf[n], acc[mq][n], 0, 0, 0); }

    ISSUE(0);
    for (int T = 0; T < NT; ++T) {
        STEP(2 * T,     0,    0)
        STEP(2 * T + 1, 4096, 8192)
    }
#undef STEP
#undef ISSUE
}

// ============ 128x128 fp16 GEMM core (pv): same schedule, 32KB LDS ============
// 8 waves (2Mrow x 4Ncol), per-wave 64x32, acc[4][2].
template<int NT>
__device__ __forceinline__ void gemm_narrow(const u16* __restrict__ A, const u16* __restrict__ Bt,
                                            int lda, int ldb, int rowbase, int colbase,
                                            u16* ldsA, u16* ldsB, f32x4 (&acc)[4][2])
{
    const int NSTEP = 2 * NT;
    const int tid  = threadIdx.x;
    const int lane = tid & 63;
    const int w    = tid >> 6;
    const int wr   = w >> 2, wc = w & 3;

    const int r0 = tid >> 2;
    const int c0 = (((tid & 3) ^ ((tid >> 3) & 3)) << 3);
    const uint32_t offA0 = (uint32_t)(rowbase + r0) * lda + c0;
    const uint32_t offB0 = (uint32_t)(colbase + r0) * ldb + c0;
    const int dst = tid << 3;

    const int rd_lane = ((lane & 15) << 5) + ((((lane >> 4) ^ (lane >> 1)) & 3) << 3);
    const int wrOff = wr << 11;           // wr*64 rows * 32 u16
    const int wcOff = wc << 10;           // wc*32 rows * 32 u16

#define ISSUE(sv) do { int s_ = (sv); \
    if (s_ < NSTEP) { \
        uint32_t ko_ = (uint32_t)s_ << 5; \
        int sl_ = (s_ & 1) << 12; \
        gload_lds16(A  + offA0 + ko_, ldsA + sl_ + dst); \
        gload_lds16(Bt + offB0 + ko_, ldsB + sl_ + dst); \
    } } while (0)

    f16x8 af[4], bf[2];

#define STEP(sv, sl) { \
    asm volatile("s_waitcnt lgkmcnt(0)" ::: "memory"); \
    __builtin_amdgcn_s_barrier(); \
    asm volatile("" ::: "memory"); \
    ISSUE((sv) + 1); \
    if ((sv) < NSTEP - 1) asm volatile("s_waitcnt vmcnt(2)" ::: "memory"); \
    else                  asm volatile("s_waitcnt vmcnt(0)" ::: "memory"); \
    __builtin_amdgcn_s_barrier(); \
    asm volatile("" ::: "memory"); \
    _Pragma("unroll") for (int mq = 0; mq < 4; ++mq) \
        af[mq] = *(const f16x8*)(ldsA + (sl) + wrOff + (mq << 9) + rd_lane); \
    _Pragma("unroll") for (int n = 0; n < 2; ++n) \
        bf[n] = *(const f16x8*)(ldsB + (sl) + wcOff + (n << 9) + rd_lane); \
    _Pragma("unroll") for (int mq = 0; mq < 4; ++mq) \
    _Pragma("unroll") for (int n = 0; n < 2; ++n) \
        acc[mq][n] = __builtin_amdgcn_mfma_f32_16x16x32_f16(af[mq], bf[n], acc[mq][n], 0, 0, 0); }

    ISSUE(0);
    for (int T = 0; T < NT; ++T) {
        STEP(2 * T,     0)
        STEP(2 * T + 1, 4096)
    }
#undef STEP
#undef ISSUE
}

// ---------------- stage 0a: fp32 -> fp16 ----------------
__global__ __launch_bounds__(256) void k_cvt_f16(const float* __restrict__ in,
                                                 u16* __restrict__ oh, int n) {
    int i = (blockIdx.x * 256 + threadIdx.x) << 3;
    if (i >= n) return;
    float4 a = *(const float4*)(in + i);
    float4 b = *(const float4*)(in + i + 4);
    ushort4 h0, h1;
    h0.x = f2h(a.x); h0.y = f2h(a.y); h0.z = f2h(a.z); h0.w = f2h(a.w);
    h1.x = f2h(b.x); h1.y = f2h(b.y); h1.z = f2h(b.z); h1.w = f2h(b.w);
    *(ushort4*)(oh + i)     = h0;
    *(ushort4*)(oh + i + 4) = h1;
}

// ---------------- stage 0b: W [R][C] fp32 -> Wt [C][R] fp16 ----------------
__global__ __launch_bounds__(256) void k_transpose_f16(const float* __restrict__ W,
                                                       u16* __restrict__ Wt, int R, int C) {
    __shared__ float t[32][33];
    int tx = threadIdx.x & 31, ty = threadIdx.x >> 5;
    int c0 = blockIdx.x << 5, r0 = blockIdx.y << 5;
#pragma unroll
    for (int i = 0; i < 4; ++i) {
        int r = (i << 3) + ty;
        t[r][tx] = W[(size_t)(r0 + r) * C + c0 + tx];
    }
    __syncthreads();
#pragma unroll
    for (int i = 0; i < 4; ++i) {
        int r = (i << 3) + ty;
        Wt[(size_t)(c0 + r) * R + r0 + tx] = f2h(t[tx][r]);
    }
}

// ---------------- stage 1: QKV = x @ W + b; store q,k row-major, v transposed ----------------
// 3 blocks/CU (LDS 48KB x3 = 144 <= 160; VGPR cap 85, uses ~64): grid 768 = exact 1.0 round.
__global__ __launch_bounds__(512, 6) void k_qkv(const u16* __restrict__ xh,
                                                const u16* __restrict__ wt,
                                                const float* __restrict__ bias,
                                                u16* __restrict__ qf, u16* __restrict__ kf,
                                                u16* __restrict__ vt) {
    __shared__ u16 lds[24576];
    f32x4 acc[4][4];
    f32x4 z = {0.f, 0.f, 0.f, 0.f};
#pragma unroll
    for (int m = 0; m < 4; ++m)
#pragma unroll
        for (int n = 0; n < 4; ++n) acc[m][n] = z;

    const int lid = blockIdx.y * 12 + blockIdx.x;
    const int swz = xcd_swz(lid, 768);
    const int bx = swz % 12, by = swz / 12;
    const int rowbase = by << 7;          // BM = 128
    const int colbase = bx << 8;          // BN = 256
    gemm_wide<16>(xh, wt, D_, D_, rowbase, colbase, lds, lds + 8192, acc);

    const int lane = threadIdx.x & 63;
    const int w = threadIdx.x >> 6;
    const int wr = w >> 2, wc = w & 3;
    const int region = colbase >> 10;     // 0=q, 1=k, 2=v
#pragma unroll
    for (int m = 0; m < 4; ++m) {
        int gr0 = rowbase + wr * 64 + m * 16 + ((lane >> 4) << 2);
#pragma unroll
        for (int n = 0; n < 4; ++n) {
            int gc = colbase + wc * 64 + n * 16 + (lane & 15);
            float bv = bias[gc];
            if (region == 0) {
#pragma unroll
                for (int r = 0; r < 4; ++r)
                    qf[(size_t)(gr0 + r) * D_ + gc] = f2h(acc[m][n][r] + bv);
            } else if (region == 1) {
                int c = gc - 1024;
#pragma unroll
                for (int r = 0; r < 4; ++r)
                    kf[(size_t)(gr0 + r) * D_ + c] = f2h(acc[m][n][r] + bv);
            } else {
                int d  = gc - 2048;
                int b  = gr0 >> 11;
                int t0 = gr0 & 2047;
                size_t base = (((size_t)b << 10) + d) * (size_t)S_ + t0;
#pragma unroll
                for (int r = 0; r < 4; ++r)
                    vt[base + r] = f2h(acc[m][n][r] + bv);
            }
        }
    }
}

// ---------------- stage 2: attn = sigmoid(32 * q @ k^T), fp16 ----------------
// Panel-grouped XCD decode: hw XCD = blockIdx.x (x fastest). All 16 row-blocks of one
// k-panel map to <=2 XCDs; q-panel (ty,tz) maps to exactly 1 XCD.
__global__ __launch_bounds__(512, 6) void k_scores(const u16* __restrict__ qf,
                                                   const u16* __restrict__ kf,
                                                   u16* __restrict__ attn) {
    __shared__ u16 lds[24576];
    f32x4 acc[4][4];
    f32x4 z = {0.f, 0.f, 0.f, 0.f};
#pragma unroll
    for (int m = 0; m < 4; ++m)
#pragma unroll
        for (int n = 0; n < 4; ++n) acc[m][n] = z;

    // grid (8, 16, 4): XCD(hw) = blockIdx.x. m = z*16+y in [0,64).
    // P = x*8 + (m>>3) in [0,64) -> panel (ty = P&15, tz = P>>4); tx = m&7.
    const int m_ = (blockIdx.z << 4) + blockIdx.y;
    const int P  = (blockIdx.x << 3) + (m_ >> 3);
    const int bx = m_ & 7, by = P & 15, b = P >> 4;

    const size_t boff = (size_t)b * S_ * D_;
    u16* att = attn + (size_t)b * S_ * S_;
    const int rowbase = by << 7, colbase = bx << 8;
    gemm_wide<16>(qf + boff, kf + boff, D_, D_, rowbase, colbase, lds, lds + 8192, acc);

    const int lane = threadIdx.x & 63;
    const int w = threadIdx.x >> 6;
    const int wr = w >> 2, wc = w & 3;
#pragma unroll
    for (int m = 0; m < 4; ++m) {
        int gr0 = rowbase + wr * 64 + m * 16 + ((lane >> 4) << 2);
#pragma unroll
        for (int n = 0; n < 4; ++n) {
            int gc = colbase + wc * 64 + n * 16 + (lane & 15);
#pragma unroll
            for (int r = 0; r < 4; ++r) {
                float sv = acc[m][n][r] * 32.0f;
                float sg = 1.0f / (1.0f + __expf(-sv));
                att[(size_t)(gr0 + r) * S_ + gc] = f2h(sg);
            }
        }
    }
}

// ---------------- stage 3: out = attn @ v  (Bt = v^T [D][S]), 128x128 ----------------
// Panel-grouped XCD decode: all 8 d-blocks of one attn panel (ty,tz) -> 1 XCD;
// vt panel (tz,tx) -> 2 XCDs.
__global__ __launch_bounds__(512, 4) void k_pv(const u16* __restrict__ attn,
                                               const u16* __restrict__ vt,
                                               float* __restrict__ out) {
    __shared__ u16 lds[16384];
    f32x4 acc[4][2];
    f32x4 z = {0.f, 0.f, 0.f, 0.f};
#pragma unroll
    for (int m = 0; m < 4; ++m)
#pragma unroll
        for (int n = 0; n < 2; ++n) acc[m][n] = z;

    // grid (8, 16, 4): XCD(hw) = blockIdx.x. m = z*16+y.
    const int m_ = (blockIdx.z << 4) + blockIdx.y;
    const int P  = (blockIdx.x << 3) + (m_ >> 3);
    const int bx = m_ & 7, by = P & 15, b = P >> 4;

    const u16* Aa = attn + (size_t)b * S_ * S_;
    const u16* Bv = vt   + (size_t)b * D_ * S_;
    float* ob     = out  + (size_t)b * S_ * D_;
    const int rowbase = by << 7, colbase = bx << 7;
    gemm_narrow<32>(Aa, Bv, S_, S_, rowbase, colbase, lds, lds + 8192, acc);

    const int lane = threadIdx.x & 63;
    const int w = threadIdx.x >> 6;
    const int wr = w >> 2, wc = w & 3;
#pragma unroll
    for (int m = 0; m < 4; ++m) {
        int gr0 = rowbase + wr * 64 + m * 16 + ((lane >> 4) << 2);
#pragma unroll
        for (int n = 0; n < 2; ++n) {
            int gc = colbase + wc * 32 + n * 16 + (lane & 15);
#pragma unroll
            for (int r = 0; r < 4; ++r)
                ob[(size_t)(gr0 + r) * D_ + gc] = acc[m][n][r];
        }
    }
}

extern "C" void kernel_launch(void* const* d_in, const int* in_sizes, int n_in,
                              void* d_out, int out_size, void* d_ws, size_t ws_size,
                              hipStream_t stream) {
    const float* x    = (const float*)d_in[0];
    const float* wqkv = (const float*)d_in[1];
    const float* bias = (const float*)d_in[2];
    float* out = (float*)d_out;

    const size_t MB = 1048576;
    uint8_t* ws = (uint8_t*)d_ws;
    u16* xh   = (u16*)(ws);              // [8192][1024] f16    16 MB
    u16* wt   = (u16*)(ws + 16 * MB);    // [3072][1024] f16     6 MB
    u16* qf   = (u16*)(ws + 32 * MB);    // [B][S][D] f16       16 MB
    u16* kf   = (u16*)(ws + 48 * MB);    // 16 MB
    u16* vt   = (u16*)(ws + 64 * MB);    // [B][D][S] f16       16 MB (ends 80 MB)
    u16* attn = (u16*)(ws);              // [B][S][S] f16 32 MB — aliases xh/wt (dead after QKV)

    k_cvt_f16<<<dim3(4096), dim3(256), 0, stream>>>(x, xh, B_ * S_ * D_);
    k_transpose_f16<<<dim3(ND3 / 32, D_ / 32), dim3(256), 0, stream>>>(wqkv, wt, D_, ND3);
    k_qkv<<<dim3(ND3 / 256, (B_ * S_) / 128), dim3(512), 0, stream>>>(xh, wt, bias, qf, kf, vt);
    k_scores<<<dim3(S_ / 256, S_ / 128, B_), dim3(512), 0, stream>>>(qf, kf, attn);
    k_pv<<<dim3(D_ / 128, S_ / 128, B_), dim3(512), 0, stream>>>(attn, vt, out);
}

// Round 12
// 161.057 us; speedup vs baseline: 3.4698x; 3.4698x over previous
//
#include <hip/hip_runtime.h>
#include <stdint.h>

typedef unsigned short u16;
typedef _Float16 f16x8 __attribute__((ext_vector_type(8)));
typedef float f32x4 __attribute__((ext_vector_type(4)));

#define B_   4
#define S_   2048
#define D_   1024
#define ND3  3072

__device__ __forceinline__ u16 f2h(float x) {
    union { _Float16 h; u16 u; } v; v.h = (_Float16)x; return v.u;
}

__device__ __forceinline__ void gload_lds16(const u16* g, u16* l) {
    __builtin_amdgcn_global_load_lds((const __attribute__((address_space(1))) void*)g,
                                     (__attribute__((address_space(3))) void*)l, 16, 0, 0);
}

// bijective XCD swizzle for nwg % 8 == 0
__device__ __forceinline__ int xcd_swz(int lid, int nwg) {
    int c = nwg >> 3;
    return (lid & 7) * c + (lid >> 3);
}

// ============ 128x256 fp16 GEMM core, K-step=32 double-buffer ============
// acc += A @ B^T, K = NT*64 (steps of 32). 512 threads = 8 waves (2Mrow x 4Ncol),
// per-wave output 64x64, acc[4][4]. LDS 48KB: A [2][128r][32k] + B [2][256r][32k].
// Swizzle: chunk c of row r stored at c ^ ((r>>1)&3), applied on global SOURCE
// (linear LDS dest) and identically on ds_read. Race-free step (proven r7/r8):
//   lgkmcnt(0); barrier; ISSUE(S+1); vmcnt(3); barrier; body (8 ds_read + 16 MFMA).
template<int NT>
__device__ __forceinline__ void gemm_wide(const u16* __restrict__ A, const u16* __restrict__ Bt,
                                          int lda, int ldb, int rowbase, int colbase,
                                          u16* ldsA, u16* ldsB, f32x4 (&acc)[4][4])
{
    const int NSTEP = 2 * NT;
    const int tid  = threadIdx.x;
    const int lane = tid & 63;
    const int w    = tid >> 6;
    const int wr   = w >> 2, wc = w & 3;

    const int r0 = tid >> 2;
    const int c0 = (((tid & 3) ^ ((tid >> 3) & 3)) << 3);
    const uint32_t offA0 = (uint32_t)(rowbase + r0) * lda + c0;
    const uint32_t offB0 = (uint32_t)(colbase + r0) * ldb + c0;
    const uint32_t offB1 = offB0 + (uint32_t)128 * ldb;
    const int dst = tid << 3;

    const int rd_lane = ((lane & 15) << 5) + ((((lane >> 4) ^ (lane >> 1)) & 3) << 3);
    const int wrOff = wr << 11;
    const int wcOff = wc << 11;

#define ISSUE(sv) do { int s_ = (sv); \
    if (s_ < NSTEP) { \
        uint32_t ko_ = (uint32_t)s_ << 5; \
        int slA_ = (s_ & 1) << 12, slB_ = (s_ & 1) << 13; \
        gload_lds16(A  + offA0 + ko_, ldsA + slA_ + dst); \
        gload_lds16(Bt + offB0 + ko_, ldsB + slB_ + dst); \
        gload_lds16(Bt + offB1 + ko_, ldsB + slB_ + dst + 4096); \
    } } while (0)

    f16x8 af[4], bf[4];

#define STEP(sv, slA, slB) { \
    asm volatile("s_waitcnt lgkmcnt(0)" ::: "memory"); \
    __builtin_amdgcn_s_barrier(); \
    asm volatile("" ::: "memory"); \
    ISSUE((sv) + 1); \
    if ((sv) < NSTEP - 1) asm volatile("s_waitcnt vmcnt(3)" ::: "memory"); \
    else                  asm volatile("s_waitcnt vmcnt(0)" ::: "memory"); \
    __builtin_amdgcn_s_barrier(); \
    asm volatile("" ::: "memory"); \
    _Pragma("unroll") for (int mq = 0; mq < 4; ++mq) \
        af[mq] = *(const f16x8*)(ldsA + (slA) + wrOff + (mq << 9) + rd_lane); \
    _Pragma("unroll") for (int n = 0; n < 4; ++n) \
        bf[n] = *(const f16x8*)(ldsB + (slB) + wcOff + (n << 9) + rd_lane); \
    _Pragma("unroll") for (int mq = 0; mq < 4; ++mq) \
    _Pragma("unroll") for (int n = 0; n < 4; ++n) \
        acc[mq][n] = __builtin_amdgcn_mfma_f32_16x16x32_f16(af[mq], bf[n], acc[mq][n], 0, 0, 0); }

    ISSUE(0);
    for (int T = 0; T < NT; ++T) {
        STEP(2 * T,     0,    0)
        STEP(2 * T + 1, 4096, 8192)
    }
#undef STEP
#undef ISSUE
}

// ============ 128x128 fp16 GEMM core (pv): same schedule, 32KB LDS ============
// 8 waves (2Mrow x 4Ncol), per-wave 64x32, acc[4][2].
template<int NT>
__device__ __forceinline__ void gemm_narrow(const u16* __restrict__ A, const u16* __restrict__ Bt,
                                            int lda, int ldb, int rowbase, int colbase,
                                            u16* ldsA, u16* ldsB, f32x4 (&acc)[4][2])
{
    const int NSTEP = 2 * NT;
    const int tid  = threadIdx.x;
    const int lane = tid & 63;
    const int w    = tid >> 6;
    const int wr   = w >> 2, wc = w & 3;

    const int r0 = tid >> 2;
    const int c0 = (((tid & 3) ^ ((tid >> 3) & 3)) << 3);
    const uint32_t offA0 = (uint32_t)(rowbase + r0) * lda + c0;
    const uint32_t offB0 = (uint32_t)(colbase + r0) * ldb + c0;
    const int dst = tid << 3;

    const int rd_lane = ((lane & 15) << 5) + ((((lane >> 4) ^ (lane >> 1)) & 3) << 3);
    const int wrOff = wr << 11;           // wr*64 rows * 32 u16
    const int wcOff = wc << 10;           // wc*32 rows * 32 u16

#define ISSUE(sv) do { int s_ = (sv); \
    if (s_ < NSTEP) { \
        uint32_t ko_ = (uint32_t)s_ << 5; \
        int sl_ = (s_ & 1) << 12; \
        gload_lds16(A  + offA0 + ko_, ldsA + sl_ + dst); \
        gload_lds16(Bt + offB0 + ko_, ldsB + sl_ + dst); \
    } } while (0)

    f16x8 af[4], bf[2];

#define STEP(sv, sl) { \
    asm volatile("s_waitcnt lgkmcnt(0)" ::: "memory"); \
    __builtin_amdgcn_s_barrier(); \
    asm volatile("" ::: "memory"); \
    ISSUE((sv) + 1); \
    if ((sv) < NSTEP - 1) asm volatile("s_waitcnt vmcnt(2)" ::: "memory"); \
    else                  asm volatile("s_waitcnt vmcnt(0)" ::: "memory"); \
    __builtin_amdgcn_s_barrier(); \
    asm volatile("" ::: "memory"); \
    _Pragma("unroll") for (int mq = 0; mq < 4; ++mq) \
        af[mq] = *(const f16x8*)(ldsA + (sl) + wrOff + (mq << 9) + rd_lane); \
    _Pragma("unroll") for (int n = 0; n < 2; ++n) \
        bf[n] = *(const f16x8*)(ldsB + (sl) + wcOff + (n << 9) + rd_lane); \
    _Pragma("unroll") for (int mq = 0; mq < 4; ++mq) \
    _Pragma("unroll") for (int n = 0; n < 2; ++n) \
        acc[mq][n] = __builtin_amdgcn_mfma_f32_16x16x32_f16(af[mq], bf[n], acc[mq][n], 0, 0, 0); }

    ISSUE(0);
    for (int T = 0; T < NT; ++T) {
        STEP(2 * T,     0)
        STEP(2 * T + 1, 4096)
    }
#undef STEP
#undef ISSUE
}

// ---------------- stage 0a: fp32 -> fp16 ----------------
__global__ __launch_bounds__(256) void k_cvt_f16(const float* __restrict__ in,
                                                 u16* __restrict__ oh, int n) {
    int i = (blockIdx.x * 256 + threadIdx.x) << 3;
    if (i >= n) return;
    float4 a = *(const float4*)(in + i);
    float4 b = *(const float4*)(in + i + 4);
    ushort4 h0, h1;
    h0.x = f2h(a.x); h0.y = f2h(a.y); h0.z = f2h(a.z); h0.w = f2h(a.w);
    h1.x = f2h(b.x); h1.y = f2h(b.y); h1.z = f2h(b.z); h1.w = f2h(b.w);
    *(ushort4*)(oh + i)     = h0;
    *(ushort4*)(oh + i + 4) = h1;
}

// ---------------- stage 0b: W [R][C] fp32 -> Wt [C][R] fp16 ----------------
__global__ __launch_bounds__(256) void k_transpose_f16(const float* __restrict__ W,
                                                       u16* __restrict__ Wt, int R, int C) {
    __shared__ float t[32][33];
    int tx = threadIdx.x & 31, ty = threadIdx.x >> 5;
    int c0 = blockIdx.x << 5, r0 = blockIdx.y << 5;
#pragma unroll
    for (int i = 0; i < 4; ++i) {
        int r = (i << 3) + ty;
        t[r][tx] = W[(size_t)(r0 + r) * C + c0 + tx];
    }
    __syncthreads();
#pragma unroll
    for (int i = 0; i < 4; ++i) {
        int r = (i << 3) + ty;
        Wt[(size_t)(c0 + r) * R + r0 + tx] = f2h(t[tx][r]);
    }
}

// ---------------- stage 1: QKV = x @ W + b; store q,k row-major, v transposed ----------------
// (512,4): natural VGPR 64, no spill (r10-proven). Do NOT raise the wave bound (r6/r11 spills).
__global__ __launch_bounds__(512, 4) void k_qkv(const u16* __restrict__ xh,
                                                const u16* __restrict__ wt,
                                                const float* __restrict__ bias,
                                                u16* __restrict__ qf, u16* __restrict__ kf,
                                                u16* __restrict__ vt) {
    __shared__ u16 lds[24576];
    f32x4 acc[4][4];
    f32x4 z = {0.f, 0.f, 0.f, 0.f};
#pragma unroll
    for (int m = 0; m < 4; ++m)
#pragma unroll
        for (int n = 0; n < 4; ++n) acc[m][n] = z;

    const int lid = blockIdx.y * 12 + blockIdx.x;
    const int swz = xcd_swz(lid, 768);
    const int bx = swz % 12, by = swz / 12;
    const int rowbase = by << 7;          // BM = 128
    const int colbase = bx << 8;          // BN = 256
    gemm_wide<16>(xh, wt, D_, D_, rowbase, colbase, lds, lds + 8192, acc);

    const int lane = threadIdx.x & 63;
    const int w = threadIdx.x >> 6;
    const int wr = w >> 2, wc = w & 3;
    const int region = colbase >> 10;     // 0=q, 1=k, 2=v
#pragma unroll
    for (int m = 0; m < 4; ++m) {
        int gr0 = rowbase + wr * 64 + m * 16 + ((lane >> 4) << 2);
#pragma unroll
        for (int n = 0; n < 4; ++n) {
            int gc = colbase + wc * 64 + n * 16 + (lane & 15);
            float bv = bias[gc];
            if (region == 0) {
#pragma unroll
                for (int r = 0; r < 4; ++r)
                    qf[(size_t)(gr0 + r) * D_ + gc] = f2h(acc[m][n][r] + bv);
            } else if (region == 1) {
                int c = gc - 1024;
#pragma unroll
                for (int r = 0; r < 4; ++r)
                    kf[(size_t)(gr0 + r) * D_ + c] = f2h(acc[m][n][r] + bv);
            } else {
                int d  = gc - 2048;
                int b  = gr0 >> 11;
                int t0 = gr0 & 2047;
                size_t base = (((size_t)b << 10) + d) * (size_t)S_ + t0;
#pragma unroll
                for (int r = 0; r < 4; ++r)
                    vt[base + r] = f2h(acc[m][n][r] + bv);
            }
        }
    }
}

// ---------------- stage 2: attn = sigmoid(32 * q @ k^T), fp16 ----------------
// Panel-grouped XCD decode: hw XCD = blockIdx.x (x-fastest linearization).
// One XCD serves 8 q-panels x 8 col-blocks -> q-panel re-reads are L2-local;
// k-panels served by <=2 XCDs.
__global__ __launch_bounds__(512, 4) void k_scores(const u16* __restrict__ qf,
                                                   const u16* __restrict__ kf,
                                                   u16* __restrict__ attn) {
    __shared__ u16 lds[24576];
    f32x4 acc[4][4];
    f32x4 z = {0.f, 0.f, 0.f, 0.f};
#pragma unroll
    for (int m = 0; m < 4; ++m)
#pragma unroll
        for (int n = 0; n < 4; ++n) acc[m][n] = z;

    // grid (8, 16, 4): m = z*16+y in [0,64); P = x*8 + (m>>3); tx = m&7.
    const int m_ = (blockIdx.z << 4) + blockIdx.y;
    const int P  = (blockIdx.x << 3) + (m_ >> 3);
    const int bx = m_ & 7, by = P & 15, b = P >> 4;

    const size_t boff = (size_t)b * S_ * D_;
    u16* att = attn + (size_t)b * S_ * S_;
    const int rowbase = by << 7, colbase = bx << 8;
    gemm_wide<16>(qf + boff, kf + boff, D_, D_, rowbase, colbase, lds, lds + 8192, acc);

    const int lane = threadIdx.x & 63;
    const int w = threadIdx.x >> 6;
    const int wr = w >> 2, wc = w & 3;
#pragma unroll
    for (int m = 0; m < 4; ++m) {
        int gr0 = rowbase + wr * 64 + m * 16 + ((lane >> 4) << 2);
#pragma unroll
        for (int n = 0; n < 4; ++n) {
            int gc = colbase + wc * 64 + n * 16 + (lane & 15);
#pragma unroll
            for (int r = 0; r < 4; ++r) {
                float sv = acc[m][n][r] * 32.0f;
                float sg = 1.0f / (1.0f + __expf(-sv));
                att[(size_t)(gr0 + r) * S_ + gc] = f2h(sg);
            }
        }
    }
}

// ---------------- stage 3: out = attn @ v  (Bt = v^T [D][S]), 128x128 ----------------
// Panel-grouped XCD decode: all 8 d-blocks of one attn panel -> 1 XCD.
__global__ __launch_bounds__(512, 4) void k_pv(const u16* __restrict__ attn,
                                               const u16* __restrict__ vt,
                                               float* __restrict__ out) {
    __shared__ u16 lds[16384];
    f32x4 acc[4][2];
    f32x4 z = {0.f, 0.f, 0.f, 0.f};
#pragma unroll
    for (int m = 0; m < 4; ++m)
#pragma unroll
        for (int n = 0; n < 2; ++n) acc[m][n] = z;

    // grid (8, 16, 4): m = z*16+y; P = x*8 + (m>>3); tx = m&7.
    const int m_ = (blockIdx.z << 4) + blockIdx.y;
    const int P  = (blockIdx.x << 3) + (m_ >> 3);
    const int bx = m_ & 7, by = P & 15, b = P >> 4;

    const u16* Aa = attn + (size_t)b * S_ * S_;
    const u16* Bv = vt   + (size_t)b * D_ * S_;
    float* ob     = out  + (size_t)b * S_ * D_;
    const int rowbase = by << 7, colbase = bx << 7;
    gemm_narrow<32>(Aa, Bv, S_, S_, rowbase, colbase, lds, lds + 8192, acc);

    const int lane = threadIdx.x & 63;
    const int w = threadIdx.x >> 6;
    const int wr = w >> 2, wc = w & 3;
#pragma unroll
    for (int m = 0; m < 4; ++m) {
        int gr0 = rowbase + wr * 64 + m * 16 + ((lane >> 4) << 2);
#pragma unroll
        for (int n = 0; n < 2; ++n) {
            int gc = colbase + wc * 32 + n * 16 + (lane & 15);
#pragma unroll
            for (int r = 0; r < 4; ++r)
                ob[(size_t)(gr0 + r) * D_ + gc] = acc[m][n][r];
        }
    }
}

extern "C" void kernel_launch(void* const* d_in, const int* in_sizes, int n_in,
                              void* d_out, int out_size, void* d_ws, size_t ws_size,
                              hipStream_t stream) {
    const float* x    = (const float*)d_in[0];
    const float* wqkv = (const float*)d_in[1];
    const float* bias = (const float*)d_in[2];
    float* out = (float*)d_out;

    const size_t MB = 1048576;
    uint8_t* ws = (uint8_t*)d_ws;
    u16* xh   = (u16*)(ws);              // [8192][1024] f16    16 MB
    u16* wt   = (u16*)(ws + 16 * MB);    // [3072][1024] f16     6 MB
    u16* qf   = (u16*)(ws + 32 * MB);    // [B][S][D] f16       16 MB
    u16* kf   = (u16*)(ws + 48 * MB);    // 16 MB
    u16* vt   = (u16*)(ws + 64 * MB);    // [B][D][S] f16       16 MB (ends 80 MB)
    u16* attn = (u16*)(ws);              // [B][S][S] f16 32 MB — aliases xh/wt (dead after QKV)

    k_cvt_f16<<<dim3(4096), dim3(256), 0, stream>>>(x, xh, B_ * S_ * D_);
    k_transpose_f16<<<dim3(ND3 / 32, D_ / 32), dim3(256), 0, stream>>>(wqkv, wt, D_, ND3);
    k_qkv<<<dim3(ND3 / 256, (B_ * S_) / 128), dim3(512), 0, stream>>>(xh, wt, bias, qf, kf, vt);
    k_scores<<<dim3(S_ / 256, S_ / 128, B_), dim3(512), 0, stream>>>(qf, kf, attn);
    k_pv<<<dim3(D_ / 128, S_ / 128, B_), dim3(512), 0, stream>>>(attn, vt, out);
}

// Round 15
// 160.834 us; speedup vs baseline: 3.4746x; 1.0014x over previous
//
#include <hip/hip_runtime.h>
#include <stdint.h>

typedef unsigned short u16;
typedef _Float16 f16x8 __attribute__((ext_vector_type(8)));
typedef float f32x4 __attribute__((ext_vector_type(4)));

#define B_   4
#define S_   2048
#define D_   1024
#define ND3  3072

__device__ __forceinline__ u16 f2h(float x) {
    union { _Float16 h; u16 u; } v; v.h = (_Float16)x; return v.u;
}

__device__ __forceinline__ void gload_lds16(const u16* g, u16* l) {
    __builtin_amdgcn_global_load_lds((const __attribute__((address_space(1))) void*)g,
                                     (__attribute__((address_space(3))) void*)l, 16, 0, 0);
}

// bijective XCD swizzle for nwg % 8 == 0
__device__ __forceinline__ int xcd_swz(int lid, int nwg) {
    int c = nwg >> 3;
    return (lid & 7) * c + (lid >> 3);
}

// ============ 128x256 fp16 GEMM core, K-step=32, RING-3 / 1-barrier ============
// acc += A @ B^T, K = NT*64 (steps of 32). 512 threads = 8 waves (2Mrow x 4Ncol),
// per-wave output 64x64, acc[4][4]. LDS 72KB: A ring 3 x 8KB + B ring 3 x 16KB.
// Swizzle (verified 0-conflict): chunk c of row r stored at c ^ ((r>>1)&3), applied
// on global SOURCE (linear LDS dest) and identically on ds_read.
// Race-free single-barrier step S (ring-3, prefetch distance 2):
//   lgkmcnt(0)                  -- own ds_reads of step S-1 (slot (S-1)%3) drained
//   vmcnt(3)  [last step: 0]    -- own B(S) DMA landed (in-order retire; B(S+1) pending)
//   barrier                     -- publishes: all reads of (S-1) drained, all B(S) landed
//   ISSUE(S+2)                  -- writes slot (S+2)%3 = (S-1)%3 (safe: drained pre-barrier)
//   body: 8 ds_read_b128 + 16 MFMA (compiler inserts fine-grained lgkm)
template<int NT>
__device__ __forceinline__ void gemm_wide(const u16* __restrict__ A, const u16* __restrict__ Bt,
                                          int lda, int ldb, int rowbase, int colbase,
                                          u16* ldsA, u16* ldsB, f32x4 (&acc)[4][4])
{
    const int NSTEP = 2 * NT;
    const int tid  = threadIdx.x;
    const int lane = tid & 63;
    const int w    = tid >> 6;
    const int wr   = w >> 2, wc = w & 3;

    const int r0 = tid >> 2;
    const int c0 = (((tid & 3) ^ ((tid >> 3) & 3)) << 3);
    const uint32_t offA0 = (uint32_t)(rowbase + r0) * lda + c0;
    const uint32_t offB0 = (uint32_t)(colbase + r0) * ldb + c0;
    const uint32_t offB1 = offB0 + (uint32_t)128 * ldb;
    const int dst = tid << 3;

    const int rd_lane = ((lane & 15) << 5) + ((((lane >> 4) ^ (lane >> 1)) & 3) << 3);
    const int wrOff = wr << 11;           // wr*64 rows * 32 u16
    const int wcOff = wc << 11;           // wc*64 rows * 32 u16

#define ISSUE(sv) do { int s_ = (sv); \
    if (s_ < NSTEP) { \
        uint32_t ko_ = (uint32_t)s_ << 5; \
        int st_ = s_ % 3; \
        int slA_ = st_ << 12;             /* slot * 4096 u16 */ \
        int slB_ = st_ << 13;             /* slot * 8192 u16 */ \
        gload_lds16(A  + offA0 + ko_, ldsA + slA_ + dst); \
        gload_lds16(Bt + offB0 + ko_, ldsB + slB_ + dst); \
        gload_lds16(Bt + offB1 + ko_, ldsB + slB_ + dst + 4096); \
    } } while (0)

    f16x8 af[4], bf[4];

    ISSUE(0); ISSUE(1);
    int sl = 0;                            // current step's slot (S % 3)
    for (int S = 0; S < NSTEP; ++S) {
        asm volatile("s_waitcnt lgkmcnt(0)" ::: "memory");
        if (S < NSTEP - 1) asm volatile("s_waitcnt vmcnt(3)" ::: "memory");
        else               asm volatile("s_waitcnt vmcnt(0)" ::: "memory");
        __builtin_amdgcn_s_barrier();
        asm volatile("" ::: "memory");
        ISSUE(S + 2);
        const int slA = sl << 12, slB = sl << 13;
#pragma unroll
        for (int mq = 0; mq < 4; ++mq)
            af[mq] = *(const f16x8*)(ldsA + slA + wrOff + (mq << 9) + rd_lane);
#pragma unroll
        for (int n = 0; n < 4; ++n)
            bf[n] = *(const f16x8*)(ldsB + slB + wcOff + (n << 9) + rd_lane);
#pragma unroll
        for (int mq = 0; mq < 4; ++mq)
#pragma unroll
            for (int n = 0; n < 4; ++n)
                acc[mq][n] = __builtin_amdgcn_mfma_f32_16x16x32_f16(af[mq], bf[n], acc[mq][n], 0, 0, 0);
        sl = (sl == 2) ? 0 : sl + 1;
    }
#undef ISSUE
}

// ============ 128x128 fp16 GEMM core (pv): ring-3 / 1-barrier, 48KB LDS ============
// 8 waves (2Mrow x 4Ncol), per-wave 64x32, acc[4][2]. 2 loads/step -> vmcnt(2).
template<int NT>
__device__ __forceinline__ void gemm_narrow(const u16* __restrict__ A, const u16* __restrict__ Bt,
                                            int lda, int ldb, int rowbase, int colbase,
                                            u16* ldsA, u16* ldsB, f32x4 (&acc)[4][2])
{
    const int NSTEP = 2 * NT;
    const int tid  = threadIdx.x;
    const int lane = tid & 63;
    const int w    = tid >> 6;
    const int wr   = w >> 2, wc = w & 3;

    const int r0 = tid >> 2;
    const int c0 = (((tid & 3) ^ ((tid >> 3) & 3)) << 3);
    const uint32_t offA0 = (uint32_t)(rowbase + r0) * lda + c0;
    const uint32_t offB0 = (uint32_t)(colbase + r0) * ldb + c0;
    const int dst = tid << 3;

    const int rd_lane = ((lane & 15) << 5) + ((((lane >> 4) ^ (lane >> 1)) & 3) << 3);
    const int wrOff = wr << 11;           // wr*64 rows * 32 u16
    const int wcOff = wc << 10;           // wc*32 rows * 32 u16

#define ISSUE(sv) do { int s_ = (sv); \
    if (s_ < NSTEP) { \
        uint32_t ko_ = (uint32_t)s_ << 5; \
        int sl_ = (s_ % 3) << 12; \
        gload_lds16(A  + offA0 + ko_, ldsA + sl_ + dst); \
        gload_lds16(Bt + offB0 + ko_, ldsB + sl_ + dst); \
    } } while (0)

    f16x8 af[4], bf[2];

    ISSUE(0); ISSUE(1);
    int sl = 0;
    for (int S = 0; S < NSTEP; ++S) {
        asm volatile("s_waitcnt lgkmcnt(0)" ::: "memory");
        if (S < NSTEP - 1) asm volatile("s_waitcnt vmcnt(2)" ::: "memory");
        else               asm volatile("s_waitcnt vmcnt(0)" ::: "memory");
        __builtin_amdgcn_s_barrier();
        asm volatile("" ::: "memory");
        ISSUE(S + 2);
        const int slo = sl << 12;
#pragma unroll
        for (int mq = 0; mq < 4; ++mq)
            af[mq] = *(const f16x8*)(ldsA + slo + wrOff + (mq << 9) + rd_lane);
#pragma unroll
        for (int n = 0; n < 2; ++n)
            bf[n] = *(const f16x8*)(ldsB + slo + wcOff + (n << 9) + rd_lane);
#pragma unroll
        for (int mq = 0; mq < 4; ++mq)
#pragma unroll
            for (int n = 0; n < 2; ++n)
                acc[mq][n] = __builtin_amdgcn_mfma_f32_16x16x32_f16(af[mq], bf[n], acc[mq][n], 0, 0, 0);
        sl = (sl == 2) ? 0 : sl + 1;
    }
#undef ISSUE
}

// ---------------- stage 0a: fp32 -> fp16 ----------------
__global__ __launch_bounds__(256) void k_cvt_f16(const float* __restrict__ in,
                                                 u16* __restrict__ oh, int n) {
    int i = (blockIdx.x * 256 + threadIdx.x) << 3;
    if (i >= n) return;
    float4 a = *(const float4*)(in + i);
    float4 b = *(const float4*)(in + i + 4);
    ushort4 h0, h1;
    h0.x = f2h(a.x); h0.y = f2h(a.y); h0.z = f2h(a.z); h0.w = f2h(a.w);
    h1.x = f2h(b.x); h1.y = f2h(b.y); h1.z = f2h(b.z); h1.w = f2h(b.w);
    *(ushort4*)(oh + i)     = h0;
    *(ushort4*)(oh + i + 4) = h1;
}

// ---------------- stage 0b: W [R][C] fp32 -> Wt [C][R] fp16 ----------------
__global__ __launch_bounds__(256) void k_transpose_f16(const float* __restrict__ W,
                                                       u16* __restrict__ Wt, int R, int C) {
    __shared__ float t[32][33];
    int tx = threadIdx.x & 31, ty = threadIdx.x >> 5;
    int c0 = blockIdx.x << 5, r0 = blockIdx.y << 5;
#pragma unroll
    for (int i = 0; i < 4; ++i) {
        int r = (i << 3) + ty;
        t[r][tx] = W[(size_t)(r0 + r) * C + c0 + tx];
    }
    __syncthreads();
#pragma unroll
    for (int i = 0; i < 4; ++i) {
        int r = (i << 3) + ty;
        Wt[(size_t)(c0 + r) * R + r0 + tx] = f2h(t[tx][r]);
    }
}

// ---------------- stage 1: QKV = x @ W + b; store q,k row-major, v transposed ----------------
// (512,4): natural VGPR ~64, no spill. Do NOT raise the wave bound (r6/r11 spills).
// LDS 72KB -> 2 blocks/CU.
__global__ __launch_bounds__(512, 4) void k_qkv(const u16* __restrict__ xh,
                                                const u16* __restrict__ wt,
                                                const float* __restrict__ bias,
                                                u16* __restrict__ qf, u16* __restrict__ kf,
                                                u16* __restrict__ vt) {
    __shared__ u16 lds[36864];            // A ring 12288 + B ring 24576
    f32x4 acc[4][4];
    f32x4 z = {0.f, 0.f, 0.f, 0.f};
#pragma unroll
    for (int m = 0; m < 4; ++m)
#pragma unroll
        for (int n = 0; n < 4; ++n) acc[m][n] = z;

    const int lid = blockIdx.y * 12 + blockIdx.x;
    const int swz = xcd_swz(lid, 768);
    const int bx = swz % 12, by = swz / 12;
    const int rowbase = by << 7;          // BM = 128
    const int colbase = bx << 8;          // BN = 256
    gemm_wide<16>(xh, wt, D_, D_, rowbase, colbase, lds, lds + 12288, acc);

    const int lane = threadIdx.x & 63;
    const int w = threadIdx.x >> 6;
    const int wr = w >> 2, wc = w & 3;
    const int region = colbase >> 10;     // 0=q, 1=k, 2=v
#pragma unroll
    for (int m = 0; m < 4; ++m) {
        int gr0 = rowbase + wr * 64 + m * 16 + ((lane >> 4) << 2);
#pragma unroll
        for (int n = 0; n < 4; ++n) {
            int gc = colbase + wc * 64 + n * 16 + (lane & 15);
            float bv = bias[gc];
            if (region == 0) {
#pragma unroll
                for (int r = 0; r < 4; ++r)
                    qf[(size_t)(gr0 + r) * D_ + gc] = f2h(acc[m][n][r] + bv);
            } else if (region == 1) {
                int c = gc - 1024;
#pragma unroll
                for (int r = 0; r < 4; ++r)
                    kf[(size_t)(gr0 + r) * D_ + c] = f2h(acc[m][n][r] + bv);
            } else {
                int d  = gc - 2048;
                int b  = gr0 >> 11;
                int t0 = gr0 & 2047;
                size_t base = (((size_t)b << 10) + d) * (size_t)S_ + t0;
#pragma unroll
                for (int r = 0; r < 4; ++r)
                    vt[base + r] = f2h(acc[m][n][r] + bv);
            }
        }
    }
}

// ---------------- stage 2: attn = sigmoid(32 * q @ k^T), fp16 ----------------
__global__ __launch_bounds__(512, 4) void k_scores(const u16* __restrict__ qf,
                                                   const u16* __restrict__ kf,
                                                   u16* __restrict__ attn) {
    __shared__ u16 lds[36864];
    f32x4 acc[4][4];
    f32x4 z = {0.f, 0.f, 0.f, 0.f};
#pragma unroll
    for (int m = 0; m < 4; ++m)
#pragma unroll
        for (int n = 0; n < 4; ++n) acc[m][n] = z;

    // grid (8, 16, 4): panel-grouped decode (neutral, kept from r12)
    const int m_ = (blockIdx.z << 4) + blockIdx.y;
    const int P  = (blockIdx.x << 3) + (m_ >> 3);
    const int bx = m_ & 7, by = P & 15, b = P >> 4;

    const size_t boff = (size_t)b * S_ * D_;
    u16* att = attn + (size_t)b * S_ * S_;
    const int rowbase = by << 7, colbase = bx << 8;
    gemm_wide<16>(qf + boff, kf + boff, D_, D_, rowbase, colbase, lds, lds + 12288, acc);

    const int lane = threadIdx.x & 63;
    const int w = threadIdx.x >> 6;
    const int wr = w >> 2, wc = w & 3;
#pragma unroll
    for (int m = 0; m < 4; ++m) {
        int gr0 = rowbase + wr * 64 + m * 16 + ((lane >> 4) << 2);
#pragma unroll
        for (int n = 0; n < 4; ++n) {
            int gc = colbase + wc * 64 + n * 16 + (lane & 15);
#pragma unroll
            for (int r = 0; r < 4; ++r) {
                float sv = acc[m][n][r] * 32.0f;
                float sg = 1.0f / (1.0f + __expf(-sv));
                att[(size_t)(gr0 + r) * S_ + gc] = f2h(sg);
            }
        }
    }
}

// ---------------- stage 3: out = attn @ v  (Bt = v^T [D][S]), 128x128 ----------------
__global__ __launch_bounds__(512, 4) void k_pv(const u16* __restrict__ attn,
                                               const u16* __restrict__ vt,
                                               float* __restrict__ out) {
    __shared__ u16 lds[24576];            // A ring 12288 + B ring 12288 (48KB)
    f32x4 acc[4][2];
    f32x4 z = {0.f, 0.f, 0.f, 0.f};
#pragma unroll
    for (int m = 0; m < 4; ++m)
#pragma unroll
        for (int n = 0; n < 2; ++n) acc[m][n] = z;

    // grid (8, 16, 4): panel-grouped decode
    const int m_ = (blockIdx.z << 4) + blockIdx.y;
    const int P  = (blockIdx.x << 3) + (m_ >> 3);
    const int bx = m_ & 7, by = P & 15, b = P >> 4;

    const u16* Aa = attn + (size_t)b * S_ * S_;
    const u16* Bv = vt   + (size_t)b * D_ * S_;
    float* ob     = out  + (size_t)b * S_ * D_;
    const int rowbase = by << 7, colbase = bx << 7;
    gemm_narrow<32>(Aa, Bv, S_, S_, rowbase, colbase, lds, lds + 12288, acc);

    const int lane = threadIdx.x & 63;
    const int w = threadIdx.x >> 6;
    const int wr = w >> 2, wc = w & 3;
#pragma unroll
    for (int m = 0; m < 4; ++m) {
        int gr0 = rowbase + wr * 64 + m * 16 + ((lane >> 4) << 2);
#pragma unroll
        for (int n = 0; n < 2; ++n) {
            int gc = colbase + wc * 32 + n * 16 + (lane & 15);
#pragma unroll
            for (int r = 0; r < 4; ++r)
                ob[(size_t)(gr0 + r) * D_ + gc] = acc[m][n][r];
        }
    }
}

extern "C" void kernel_launch(void* const* d_in, const int* in_sizes, int n_in,
                              void* d_out, int out_size, void* d_ws, size_t ws_size,
                              hipStream_t stream) {
    const float* x    = (const float*)d_in[0];
    const float* wqkv = (const float*)d_in[1];
    const float* bias = (const float*)d_in[2];
    float* out = (float*)d_out;

    const size_t MB = 1048576;
    uint8_t* ws = (uint8_t*)d_ws;
    u16* xh   = (u16*)(ws);              // [8192][1024] f16    16 MB
    u16* wt   = (u16*)(ws + 16 * MB);    // [3072][1024] f16     6 MB
    u16* qf   = (u16*)(ws + 32 * MB);    // [B][S][D] f16       16 MB
    u16* kf   = (u16*)(ws + 48 * MB);    // 16 MB
    u16* vt   = (u16*)(ws + 64 * MB);    // [B][D][S] f16       16 MB (ends 80 MB)
    u16* attn = (u16*)(ws);              // [B][S][S] f16 32 MB — aliases xh/wt (dead after QKV)

    k_cvt_f16<<<dim3(4096), dim3(256), 0, stream>>>(x, xh, B_ * S_ * D_);
    k_transpose_f16<<<dim3(ND3 / 32, D_ / 32), dim3(256), 0, stream>>>(wqkv, wt, D_, ND3);
    k_qkv<<<dim3(ND3 / 256, (B_ * S_) / 128), dim3(512), 0, stream>>>(xh, wt, bias, qf, kf, vt);
    k_scores<<<dim3(S_ / 256, S_ / 128, B_), dim3(512), 0, stream>>>(qf, kf, attn);
    k_pv<<<dim3(D_ / 128, S_ / 128, B_), dim3(512), 0, stream>>>(attn, vt, out);
}

// Round 16
// 156.616 us; speedup vs baseline: 3.5681x; 1.0269x over previous
//
#include <hip/hip_runtime.h>
#include <stdint.h>

typedef unsigned short u16;
typedef _Float16 f16x8 __attribute__((ext_vector_type(8)));
typedef float f32x4 __attribute__((ext_vector_type(4)));

#define B_   4
#define S_   2048
#define D_   1024
#define ND3  3072

__device__ __forceinline__ u16 f2h(float x) {
    union { _Float16 h; u16 u; } v; v.h = (_Float16)x; return v.u;
}

__device__ __forceinline__ void gload_lds16(const u16* g, u16* l) {
    __builtin_amdgcn_global_load_lds((const __attribute__((address_space(1))) void*)g,
                                     (__attribute__((address_space(3))) void*)l, 16, 0, 0);
}

// bijective XCD swizzle for nwg % 8 == 0
__device__ __forceinline__ int xcd_swz(int lid, int nwg) {
    int c = nwg >> 3;
    return (lid & 7) * c + (lid >> 3);
}

// ============ 128x256 fp16 GEMM core, K-step=32, RING-3 / 1-barrier ============
// acc += A @ B^T, K = NT*64 (steps of 32). 512 threads = 8 waves (2Mrow x 4Ncol),
// per-wave output 64x64, acc[4][4]. LDS 72KB: A ring 3 x 8KB + B ring 3 x 16KB.
// Swizzle (verified 0-conflict): chunk c of row r stored at c ^ ((r>>1)&3), applied
// on global SOURCE (linear LDS dest) and identically on ds_read.
// Race-free single-barrier step S (ring-3, prefetch distance 2) — r15-verified.
template<int NT>
__device__ __forceinline__ void gemm_wide(const u16* __restrict__ A, const u16* __restrict__ Bt,
                                          int lda, int ldb, int rowbase, int colbase,
                                          u16* ldsA, u16* ldsB, f32x4 (&acc)[4][4])
{
    const int NSTEP = 2 * NT;
    const int tid  = threadIdx.x;
    const int lane = tid & 63;
    const int w    = tid >> 6;
    const int wr   = w >> 2, wc = w & 3;

    const int r0 = tid >> 2;
    const int c0 = (((tid & 3) ^ ((tid >> 3) & 3)) << 3);
    const uint32_t offA0 = (uint32_t)(rowbase + r0) * lda + c0;
    const uint32_t offB0 = (uint32_t)(colbase + r0) * ldb + c0;
    const uint32_t offB1 = offB0 + (uint32_t)128 * ldb;
    const int dst = tid << 3;

    const int rd_lane = ((lane & 15) << 5) + ((((lane >> 4) ^ (lane >> 1)) & 3) << 3);
    const int wrOff = wr << 11;           // wr*64 rows * 32 u16
    const int wcOff = wc << 11;           // wc*64 rows * 32 u16

#define ISSUE(sv) do { int s_ = (sv); \
    if (s_ < NSTEP) { \
        uint32_t ko_ = (uint32_t)s_ << 5; \
        int st_ = s_ % 3; \
        int slA_ = st_ << 12; \
        int slB_ = st_ << 13; \
        gload_lds16(A  + offA0 + ko_, ldsA + slA_ + dst); \
        gload_lds16(Bt + offB0 + ko_, ldsB + slB_ + dst); \
        gload_lds16(Bt + offB1 + ko_, ldsB + slB_ + dst + 4096); \
    } } while (0)

    f16x8 af[4], bf[4];

    ISSUE(0); ISSUE(1);
    int sl = 0;
    for (int S = 0; S < NSTEP; ++S) {
        asm volatile("s_waitcnt lgkmcnt(0)" ::: "memory");
        if (S < NSTEP - 1) asm volatile("s_waitcnt vmcnt(3)" ::: "memory");
        else               asm volatile("s_waitcnt vmcnt(0)" ::: "memory");
        __builtin_amdgcn_s_barrier();
        asm volatile("" ::: "memory");
        ISSUE(S + 2);
        const int slA = sl << 12, slB = sl << 13;
#pragma unroll
        for (int mq = 0; mq < 4; ++mq)
            af[mq] = *(const f16x8*)(ldsA + slA + wrOff + (mq << 9) + rd_lane);
#pragma unroll
        for (int n = 0; n < 4; ++n)
            bf[n] = *(const f16x8*)(ldsB + slB + wcOff + (n << 9) + rd_lane);
#pragma unroll
        for (int mq = 0; mq < 4; ++mq)
#pragma unroll
            for (int n = 0; n < 4; ++n)
                acc[mq][n] = __builtin_amdgcn_mfma_f32_16x16x32_f16(af[mq], bf[n], acc[mq][n], 0, 0, 0);
        sl = (sl == 2) ? 0 : sl + 1;
    }
#undef ISSUE
}

// ---------------- stage 0: fused prep — x fp32->fp16 (blocks 0..4095) + W transpose (4096..7167) ----------------
__global__ __launch_bounds__(256) void k_prep(const float* __restrict__ x, u16* __restrict__ xh,
                                              const float* __restrict__ W, u16* __restrict__ Wt) {
    __shared__ float t[32][33];
    int bb = blockIdx.x;
    if (bb < 4096) {
        int i = (bb * 256 + threadIdx.x) << 3;
        if (i >= B_ * S_ * D_) return;
        float4 a = *(const float4*)(x + i);
        float4 b = *(const float4*)(x + i + 4);
        ushort4 h0, h1;
        h0.x = f2h(a.x); h0.y = f2h(a.y); h0.z = f2h(a.z); h0.w = f2h(a.w);
        h1.x = f2h(b.x); h1.y = f2h(b.y); h1.z = f2h(b.z); h1.w = f2h(b.w);
        *(ushort4*)(xh + i)     = h0;
        *(ushort4*)(xh + i + 4) = h1;
    } else {
        bb -= 4096;                        // W [1024][3072] -> Wt [3072][1024]
        int c0 = (bb % 96) << 5, r0 = (bb / 96) << 5;
        int tx = threadIdx.x & 31, ty = threadIdx.x >> 5;
#pragma unroll
        for (int i = 0; i < 4; ++i) {
            int r = (i << 3) + ty;
            t[r][tx] = W[(size_t)(r0 + r) * ND3 + c0 + tx];
        }
        __syncthreads();
#pragma unroll
        for (int i = 0; i < 4; ++i) {
            int r = (i << 3) + ty;
            Wt[(size_t)(c0 + r) * D_ + r0 + tx] = f2h(t[tx][r]);
        }
    }
}

// ---------------- stage 1: QKV = x @ W + b; store q,k row-major, v transposed ----------------
// (512,4): natural VGPR 64, no spill. Do NOT raise the wave bound (r6/r11 spills).
__global__ __launch_bounds__(512, 4) void k_qkv(const u16* __restrict__ xh,
                                                const u16* __restrict__ wt,
                                                const float* __restrict__ bias,
                                                u16* __restrict__ qf, u16* __restrict__ kf,
                                                u16* __restrict__ vt) {
    __shared__ u16 lds[36864];
    f32x4 acc[4][4];
    f32x4 z = {0.f, 0.f, 0.f, 0.f};
#pragma unroll
    for (int m = 0; m < 4; ++m)
#pragma unroll
        for (int n = 0; n < 4; ++n) acc[m][n] = z;

    const int lid = blockIdx.y * 12 + blockIdx.x;
    const int swz = xcd_swz(lid, 768);
    const int bx = swz % 12, by = swz / 12;
    const int rowbase = by << 7;          // BM = 128
    const int colbase = bx << 8;          // BN = 256
    gemm_wide<16>(xh, wt, D_, D_, rowbase, colbase, lds, lds + 12288, acc);

    const int lane = threadIdx.x & 63;
    const int w = threadIdx.x >> 6;
    const int wr = w >> 2, wc = w & 3;
    const int region = colbase >> 10;     // 0=q, 1=k, 2=v
#pragma unroll
    for (int m = 0; m < 4; ++m) {
        int gr0 = rowbase + wr * 64 + m * 16 + ((lane >> 4) << 2);
#pragma unroll
        for (int n = 0; n < 4; ++n) {
            int gc = colbase + wc * 64 + n * 16 + (lane & 15);
            float bv = bias[gc];
            if (region == 0) {
#pragma unroll
                for (int r = 0; r < 4; ++r)
                    qf[(size_t)(gr0 + r) * D_ + gc] = f2h(acc[m][n][r] + bv);
            } else if (region == 1) {
                int c = gc - 1024;
#pragma unroll
                for (int r = 0; r < 4; ++r)
                    kf[(size_t)(gr0 + r) * D_ + c] = f2h(acc[m][n][r] + bv);
            } else {
                int d  = gc - 2048;
                int b  = gr0 >> 11;
                int t0 = gr0 & 2047;
                size_t base = (((size_t)b << 10) + d) * (size_t)S_ + t0;
#pragma unroll
                for (int r = 0; r < 4; ++r)
                    vt[base + r] = f2h(acc[m][n][r] + bv);
            }
        }
    }
}

// ---------------- stage 2: attn = sigmoid(32 * q @ k^T), fp16 ----------------
__global__ __launch_bounds__(512, 4) void k_scores(const u16* __restrict__ qf,
                                                   const u16* __restrict__ kf,
                                                   u16* __restrict__ attn) {
    __shared__ u16 lds[36864];
    f32x4 acc[4][4];
    f32x4 z = {0.f, 0.f, 0.f, 0.f};
#pragma unroll
    for (int m = 0; m < 4; ++m)
#pragma unroll
        for (int n = 0; n < 4; ++n) acc[m][n] = z;

    // grid (8, 16, 4): panel-grouped decode (neutral)
    const int m_ = (blockIdx.z << 4) + blockIdx.y;
    const int P  = (blockIdx.x << 3) + (m_ >> 3);
    const int bx = m_ & 7, by = P & 15, b = P >> 4;

    const size_t boff = (size_t)b * S_ * D_;
    u16* att = attn + (size_t)b * S_ * S_;
    const int rowbase = by << 7, colbase = bx << 8;
    gemm_wide<16>(qf + boff, kf + boff, D_, D_, rowbase, colbase, lds, lds + 12288, acc);

    const int lane = threadIdx.x & 63;
    const int w = threadIdx.x >> 6;
    const int wr = w >> 2, wc = w & 3;
#pragma unroll
    for (int m = 0; m < 4; ++m) {
        int gr0 = rowbase + wr * 64 + m * 16 + ((lane >> 4) << 2);
#pragma unroll
        for (int n = 0; n < 4; ++n) {
            int gc = colbase + wc * 64 + n * 16 + (lane & 15);
#pragma unroll
            for (int r = 0; r < 4; ++r) {
                float sv = acc[m][n][r] * 32.0f;
                float sg = 1.0f / (1.0f + __expf(-sv));
                att[(size_t)(gr0 + r) * S_ + gc] = f2h(sg);
            }
        }
    }
}

// ---------------- stage 3: out = attn @ v  (Bt = v^T [D][S]), WIDE 128x256 ----------------
// grid (4, 16, 4) = 256 blocks = 1/CU. Wide core: 0.5 KB LDS-read/MFMA vs narrow 1.0.
__global__ __launch_bounds__(512, 4) void k_pv(const u16* __restrict__ attn,
                                               const u16* __restrict__ vt,
                                               float* __restrict__ out) {
    __shared__ u16 lds[36864];
    f32x4 acc[4][4];
    f32x4 z = {0.f, 0.f, 0.f, 0.f};
#pragma unroll
    for (int m = 0; m < 4; ++m)
#pragma unroll
        for (int n = 0; n < 4; ++n) acc[m][n] = z;

    const int lid = (blockIdx.z << 6) + (blockIdx.y << 2) + blockIdx.x;
    const int swz = xcd_swz(lid, 256);
    const int bx = swz & 3, by = (swz >> 2) & 15, b = swz >> 6;

    const u16* Aa = attn + (size_t)b * S_ * S_;
    const u16* Bv = vt   + (size_t)b * D_ * S_;
    float* ob     = out  + (size_t)b * S_ * D_;
    const int rowbase = by << 7, colbase = bx << 8;
    gemm_wide<32>(Aa, Bv, S_, S_, rowbase, colbase, lds, lds + 12288, acc);

    const int lane = threadIdx.x & 63;
    const int w = threadIdx.x >> 6;
    const int wr = w >> 2, wc = w & 3;
#pragma unroll
    for (int m = 0; m < 4; ++m) {
        int gr0 = rowbase + wr * 64 + m * 16 + ((lane >> 4) << 2);
#pragma unroll
        for (int n = 0; n < 4; ++n) {
            int gc = colbase + wc * 64 + n * 16 + (lane & 15);
#pragma unroll
            for (int r = 0; r < 4; ++r)
                ob[(size_t)(gr0 + r) * D_ + gc] = acc[m][n][r];
        }
    }
}

extern "C" void kernel_launch(void* const* d_in, const int* in_sizes, int n_in,
                              void* d_out, int out_size, void* d_ws, size_t ws_size,
                              hipStream_t stream) {
    const float* x    = (const float*)d_in[0];
    const float* wqkv = (const float*)d_in[1];
    const float* bias = (const float*)d_in[2];
    float* out = (float*)d_out;

    const size_t MB = 1048576;
    uint8_t* ws = (uint8_t*)d_ws;
    u16* xh   = (u16*)(ws);              // [8192][1024] f16    16 MB
    u16* wt   = (u16*)(ws + 16 * MB);    // [3072][1024] f16     6 MB
    u16* qf   = (u16*)(ws + 32 * MB);    // [B][S][D] f16       16 MB
    u16* kf   = (u16*)(ws + 48 * MB);    // 16 MB
    u16* vt   = (u16*)(ws + 64 * MB);    // [B][D][S] f16       16 MB (ends 80 MB)
    u16* attn = (u16*)(ws);              // [B][S][S] f16 32 MB — aliases xh/wt (dead after QKV)

    k_prep<<<dim3(4096 + 3072), dim3(256), 0, stream>>>(x, xh, wqkv, wt);
    k_qkv<<<dim3(ND3 / 256, (B_ * S_) / 128), dim3(512), 0, stream>>>(xh, wt, bias, qf, kf, vt);
    k_scores<<<dim3(S_ / 256, S_ / 128, B_), dim3(512), 0, stream>>>(qf, kf, attn);
    k_pv<<<dim3(D_ / 256, S_ / 128, B_), dim3(512), 0, stream>>>(attn, vt, out);
}